// Round 5
// baseline (531.725 us; speedup 1.0000x reference)
//
#include <hip/hip_runtime.h>

typedef __attribute__((ext_vector_type(4))) float float4_t;
typedef __attribute__((ext_vector_type(8))) short short8_t;
typedef __attribute__((ext_vector_type(4))) unsigned short ushort4_t;

#define B_ 8
#define S_ 14
#define P_ 196      // S*S
#define N_ 1568     // B*P
#define D_ 2048
#define C_ 20
#define WD_ 300
#define I_ 1024
#define PS_ 14      // p-splits in semantic partial
#define HLD 1025    // LDS row stride for h tile (break bank alignment)

__device__ __forceinline__ unsigned short f2bf(float f) {
    unsigned u = __builtin_bit_cast(unsigned, f);
    u += 0x7FFFu + ((u >> 16) & 1u);   // round-to-nearest-even
    return (unsigned short)(u >> 16);
}

// ---------------- fused: fp32->bf16 cvt (blocks 0..5183) + prep (5184..5280) ----------------
__global__ __launch_bounds__(256) void cvt_prep_kernel(const float* __restrict__ img,
                                                       const float* __restrict__ W1,
                                                       unsigned short* __restrict__ Xb,
                                                       unsigned short* __restrict__ W1b,
                                                       const float* __restrict__ wf,
                                                       const float* __restrict__ W2,
                                                       const float* __restrict__ W3,
                                                       const float* __restrict__ b3,
                                                       const float* __restrict__ W4,
                                                       const float* __restrict__ b4,
                                                       float* __restrict__ hw,
                                                       float* __restrict__ we,
                                                       float* __restrict__ bias) {
    int bid = blockIdx.x, tid = threadIdx.x;
    if (bid < 5184) {
        const float* src;
        unsigned short* dst;
        int i4;
        if (bid < 3136) { i4 = bid * 256 + tid; src = img; dst = Xb; }
        else            { i4 = (bid - 3136) * 256 + tid; src = W1; dst = W1b; }
        float4_t v = ((const float4_t*)src)[i4];
        ushort4_t o;
        o.x = f2bf(v.x); o.y = f2bf(v.y); o.z = f2bf(v.z); o.w = f2bf(v.w);
        ((ushort4_t*)dst)[i4] = o;
        return;
    }
    int pb = bid - 5184;
    if (pb < 80) {
        // hw[c,i] = sum_k wf[c,k] * W2[i,k]
        int idx = pb * 256 + tid;
        int c = idx >> 10, i = idx & 1023;
        const float* wr  = wf + c * WD_;
        const float* w2r = W2 + i * WD_;
        float s = 0.f;
        #pragma unroll 4
        for (int k = 0; k < WD_; k++) s += wr[k] * w2r[k];
        hw[idx] = s;
    } else if (pb < 96) {
        // we[i] = sum_j W4[j] * W3[j,i]; 16 blocks x 64 cols, 4-way j split
        __shared__ float red[256];
        int blk = pb - 80;
        int i0 = blk * 64;
        int q = tid >> 6, col = tid & 63;
        float s = 0.f;
        #pragma unroll 4
        for (int j = q * 256; j < q * 256 + 256; j++)
            s += W4[j] * W3[j * I_ + i0 + col];
        red[tid] = s;
        __syncthreads();
        if (tid < 64)
            we[i0 + tid] = red[tid] + red[tid + 64] + red[tid + 128] + red[tid + 192];
    } else {
        // bias = dot(b3, W4) + b4[0]
        __shared__ float r[256];
        float s = 0.f;
        for (int j = tid; j < I_; j += 256) s += b3[j] * W4[j];
        r[tid] = s;
        __syncthreads();
        for (int o = 128; o > 0; o >>= 1) {
            if (tid < o) r[tid] += r[tid + o];
            __syncthreads();
        }
        if (tid == 0) bias[0] = r[0] + b4[0];
    }
}

// ---------------- fused GEMM + logits: 98 blocks x 1024 threads ----------------
// Block owns 16 spatial rows x all 1024 intermediate cols. 16 waves:
//   kjob = wave>>3 (K half), nsl = wave&7 (128-col slice).
// K-loop: direct L2 loads (W1b panel is L2-resident), 8 MFMA / k-step / wave.
// h[16][1024] lives only in LDS; kjob0 writes, kjob1 adds, then per-row tanh-dot.
__global__ __launch_bounds__(1024) void gemm_logits_kernel(const unsigned short* __restrict__ Xb,
                                                           const unsigned short* __restrict__ W1b,
                                                           const float* __restrict__ hw,
                                                           const float* __restrict__ we,
                                                           const float* __restrict__ bias,
                                                           float* __restrict__ lg) {
    __shared__ float hsh[16 * HLD];
    __shared__ float sw[I_];
    int tid = threadIdx.x;
    int wave = tid >> 6, lane = tid & 63;
    int kjob = wave >> 3, nsl = wave & 7;
    int n0 = nsl * 128;
    int m0 = blockIdx.x * 16;
    int ra = lane & 15, kq = (lane >> 4) * 8;
    int kbase = kjob * 1024;
    sw[tid] = we[tid];

    const unsigned short* xa = Xb  + (size_t)(m0 + ra) * D_ + kbase + kq;
    const unsigned short* wb = W1b + (size_t)(n0 + ra) * D_ + kbase + kq;

    float4_t acc[8] = {};
    #pragma unroll 2
    for (int k0 = 0; k0 < 1024; k0 += 32) {
        short8_t a = *(const short8_t*)(xa + k0);
        #pragma unroll
        for (int f = 0; f < 8; f++) {
            short8_t b = *(const short8_t*)(wb + f * 16 * D_ + k0);
            acc[f] = __builtin_amdgcn_mfma_f32_16x16x32_bf16(a, b, acc[f], 0, 0, 0);
        }
    }

    int col16 = lane & 15, rq = (lane >> 4) * 4;
    if (kjob == 0) {
        #pragma unroll
        for (int f = 0; f < 8; f++) {
            float4_t v = acc[f];
            float* hp = &hsh[rq * HLD + n0 + f * 16 + col16];
            hp[0] = v.x; hp[HLD] = v.y; hp[2 * HLD] = v.z; hp[3 * HLD] = v.w;
        }
    }
    __syncthreads();
    if (kjob == 1) {
        #pragma unroll
        for (int f = 0; f < 8; f++) {
            float4_t v = acc[f];
            float* hp = &hsh[rq * HLD + n0 + f * 16 + col16];
            hp[0] += v.x; hp[HLD] += v.y; hp[2 * HLD] += v.z; hp[3 * HLD] += v.w;
        }
    }
    __syncthreads();

    // logits: wave w handles spatial row m0+w; 20 classes, dot over I with tanh
    int r = wave;
    float bz = bias[0];
    const float* hr = &hsh[r * HLD];
    for (int c = 0; c < C_; c++) {
        const float* hwc = hw + c * I_;
        float a0 = 0.f;
        #pragma unroll 4
        for (int i = lane; i < I_; i += 64) {
            float x = hr[i] * hwc[i];
            float t = 1.f - __fdividef(2.f, __expf(2.f * x) + 1.f);
            a0 += t * sw[i];
        }
        #pragma unroll
        for (int o = 32; o > 0; o >>= 1) a0 += __shfl_down(a0, o);
        if (lane == 0) lg[(m0 + r) * C_ + c] = a0 + bz;
    }
}

// ---------------- softmax over 196 positions per (b,c); write coef output ----------------
__global__ __launch_bounds__(256) void softmax_kernel(const float* __restrict__ lg,
                                                      float* __restrict__ coef) {
    __shared__ float r[4];
    __shared__ float bval;
    int bx = blockIdx.x;
    int b = bx / C_, c = bx % C_;
    int tid = threadIdx.x, wv = tid >> 6, lane = tid & 63;
    float v = (tid < P_) ? lg[(b * P_ + tid) * C_ + c] : -3.0e38f;
    float m = v;
    #pragma unroll
    for (int o = 32; o > 0; o >>= 1) m = fmaxf(m, __shfl_down(m, o));
    if (lane == 0) r[wv] = m;
    __syncthreads();
    if (tid == 0) bval = fmaxf(fmaxf(r[0], r[1]), fmaxf(r[2], r[3]));
    __syncthreads();
    float mx = bval;
    float e = (tid < P_) ? __expf(v - mx) : 0.f;
    float s = e;
    #pragma unroll
    for (int o = 32; o > 0; o >>= 1) s += __shfl_down(s, o);
    __syncthreads();
    if (lane == 0) r[wv] = s;
    __syncthreads();
    if (tid == 0) bval = r[0] + r[1] + r[2] + r[3];
    __syncthreads();
    if (tid < P_) coef[(b * P_ + tid) * C_ + c] = e / bval;
}

// ---------------- fmwc[b,p,c,d] = img[b,p,d] * coef[b,p,c] (high-occupancy: 6272 waves) ----------------
__global__ __launch_bounds__(256) void fmwc_kernel(const float* __restrict__ img,
                                                   const float* __restrict__ coef,
                                                   float* __restrict__ fm) {
    __shared__ float sc[C_];
    int bp = blockIdx.x, tid = threadIdx.x;
    if (tid < C_) sc[tid] = coef[bp * C_ + tid];
    __syncthreads();
    const float4_t* ir = (const float4_t*)(img + (size_t)bp * D_);
    float4_t v0 = ir[tid], v1 = ir[tid + 256];
    float4_t* ob = (float4_t*)(fm + (size_t)bp * C_ * D_);
    #pragma unroll
    for (int c = 0; c < C_; c++) {
        float s = sc[c];
        ob[c * 512 + tid] = v0 * s;
        ob[c * 512 + tid + 256] = v1 * s;
    }
}

// ---------------- semantic partials: block (ps,b,ch) reads img once, all 20 c in regs ----------------
__global__ __launch_bounds__(256) void semantic_part_kernel(const float* __restrict__ img,
                                                            const float* __restrict__ coef,
                                                            float* __restrict__ part) {
    __shared__ float sc[PS_ * C_];
    int bx = blockIdx.x;
    int ps = bx >> 4;           // 0..13
    int b = (bx >> 1) & 7;
    int ch = bx & 1;
    int tid = threadIdx.x;
    for (int q = tid; q < PS_ * C_; q += 256)
        sc[q] = coef[(b * P_ + ps * PS_) * C_ + q];
    __syncthreads();
    const float4_t* base = (const float4_t*)(img + (size_t)(b * P_ + ps * PS_) * D_ + ch * 1024) + tid;
    float4_t acc[C_];
    #pragma unroll
    for (int c = 0; c < C_; c++) acc[c] = (float4_t){0.f, 0.f, 0.f, 0.f};
    for (int pp = 0; pp < PS_; pp++) {
        float4_t v = base[pp * 512];
        #pragma unroll
        for (int c = 0; c < C_; c++) acc[c] += v * sc[pp * C_ + c];
    }
    float* pb = part + ((size_t)(ps * B_ + b) * C_) * D_ + ch * 1024 + tid * 4;
    #pragma unroll
    for (int c = 0; c < C_; c++) *(float4_t*)(pb + c * D_) = acc[c];
}

// ---------------- semantic reduce over 14 p-splits ----------------
__global__ __launch_bounds__(256) void semantic_reduce_kernel(const float* __restrict__ part,
                                                              float* __restrict__ sem) {
    int idx = blockIdx.x * 256 + threadIdx.x;   // float4 index over B*C*D/4 = 81920
    const float4_t* p4 = (const float4_t*)part;
    float4_t s = {0.f, 0.f, 0.f, 0.f};
    #pragma unroll
    for (int ps = 0; ps < PS_; ps++) s += p4[(size_t)ps * 81920 + idx];
    ((float4_t*)sem)[idx] = s;
}

extern "C" void kernel_launch(void* const* d_in, const int* in_sizes, int n_in,
                              void* d_out, int out_size, void* d_ws, size_t ws_size,
                              hipStream_t stream) {
    const float* img = (const float*)d_in[0];
    const float* wf  = (const float*)d_in[1];
    const float* W1  = (const float*)d_in[2];
    const float* W2  = (const float*)d_in[3];
    const float* W3  = (const float*)d_in[4];
    const float* b3  = (const float*)d_in[5];
    const float* W4  = (const float*)d_in[6];
    const float* b4  = (const float*)d_in[7];

    float* out  = (float*)d_out;
    float* sem  = out;                                  // [B,C,D]      = 327680
    float* fm   = out + (size_t)B_ * C_ * D_;           // [B,S,S,C,D]  = 64225280
    float* coef = fm + (size_t)N_ * C_ * D_;            // [B,S,S,C]    = 31360

    char* ws = (char*)d_ws;
    unsigned short* Xb  = (unsigned short*)ws;                  // 6,422,528 B
    unsigned short* W1b = (unsigned short*)(ws + 6422528);      // 4,194,304 B
    float* hw   = (float*)(ws + 10616832);                      // 81,920 B
    float* we   = (float*)(ws + 10698752);                      // 4,096 B
    float* bias = (float*)(ws + 10702848);                      // 256 B
    float* lg   = (float*)(ws + 10703104);                      // 125,440 B
    float* part = (float*)(ws + 10828544);                      // 14*8*20*2048*4 = 18,350,080 B

    cvt_prep_kernel<<<5281, 256, 0, stream>>>(img, W1, Xb, W1b, wf, W2, W3, b3, W4, b4, hw, we, bias);
    gemm_logits_kernel<<<98, 1024, 0, stream>>>(Xb, W1b, hw, we, bias, lg);
    softmax_kernel<<<B_ * C_, 256, 0, stream>>>(lg, coef);
    semantic_part_kernel<<<PS_ * B_ * 2, 256, 0, stream>>>(img, coef, part);
    semantic_reduce_kernel<<<320, 256, 0, stream>>>(part, sem);
    fmwc_kernel<<<N_, 256, 0, stream>>>(img, coef, fm);
}

// Round 6
// 403.481 us; speedup vs baseline: 1.3178x; 1.3178x over previous
//
#include <hip/hip_runtime.h>

typedef __attribute__((ext_vector_type(4))) float float4_t;
typedef __attribute__((ext_vector_type(8))) short short8_t;
typedef __attribute__((ext_vector_type(4))) unsigned short ushort4_t;

#define B_ 8
#define S_ 14
#define P_ 196      // S*S
#define N_ 1568     // B*P
#define D_ 2048
#define C_ 20
#define WD_ 300
#define I_ 1024
#define PS_ 14      // p-splits in semantic partial
#define LROW 72     // LDS row stride in bf16 (64 data + 8 pad): 144B, 16B-aligned, ~2-way banks

__device__ __forceinline__ unsigned short f2bf(float f) {
    unsigned u = __builtin_bit_cast(unsigned, f);
    u += 0x7FFFu + ((u >> 16) & 1u);   // round-to-nearest-even
    return (unsigned short)(u >> 16);
}

// ---------------- fused: fp32->bf16 cvt (blocks 0..5183) + prep (5184..5280) ----------------
__global__ __launch_bounds__(256) void cvt_prep_kernel(const float* __restrict__ img,
                                                       const float* __restrict__ W1,
                                                       unsigned short* __restrict__ Xb,
                                                       unsigned short* __restrict__ W1b,
                                                       const float* __restrict__ wf,
                                                       const float* __restrict__ W2,
                                                       const float* __restrict__ W3,
                                                       const float* __restrict__ b3,
                                                       const float* __restrict__ W4,
                                                       const float* __restrict__ b4,
                                                       float* __restrict__ hw,
                                                       float* __restrict__ we,
                                                       float* __restrict__ bias) {
    int bid = blockIdx.x, tid = threadIdx.x;
    if (bid < 5184) {
        const float* src;
        unsigned short* dst;
        int i4;
        if (bid < 3136) { i4 = bid * 256 + tid; src = img; dst = Xb; }
        else            { i4 = (bid - 3136) * 256 + tid; src = W1; dst = W1b; }
        float4_t v = ((const float4_t*)src)[i4];
        ushort4_t o;
        o.x = f2bf(v.x); o.y = f2bf(v.y); o.z = f2bf(v.z); o.w = f2bf(v.w);
        ((ushort4_t*)dst)[i4] = o;
        return;
    }
    int pb = bid - 5184;
    if (pb < 80) {
        // hw[c,i] = sum_k wf[c,k] * W2[i,k]
        int idx = pb * 256 + tid;
        int c = idx >> 10, i = idx & 1023;
        const float* wr  = wf + c * WD_;
        const float* w2r = W2 + i * WD_;
        float s = 0.f;
        #pragma unroll 4
        for (int k = 0; k < WD_; k++) s += wr[k] * w2r[k];
        hw[idx] = s;
    } else if (pb < 96) {
        // we[i] = sum_j W4[j] * W3[j,i]; 16 blocks x 64 cols, 4-way j split
        __shared__ float red[256];
        int blk = pb - 80;
        int i0 = blk * 64;
        int q = tid >> 6, col = tid & 63;
        float s = 0.f;
        #pragma unroll 4
        for (int j = q * 256; j < q * 256 + 256; j++)
            s += W4[j] * W3[j * I_ + i0 + col];
        red[tid] = s;
        __syncthreads();
        if (tid < 64)
            we[i0 + tid] = red[tid] + red[tid + 64] + red[tid + 128] + red[tid + 192];
    } else {
        // bias = dot(b3, W4) + b4[0]
        __shared__ float r[256];
        float s = 0.f;
        for (int j = tid; j < I_; j += 256) s += b3[j] * W4[j];
        r[tid] = s;
        __syncthreads();
        for (int o = 128; o > 0; o >>= 1) {
            if (tid < o) r[tid] += r[tid + o];
            __syncthreads();
        }
        if (tid == 0) bias[0] = r[0] + b4[0];
    }
}

// ---------------- h_img = X @ W1^T, LDS-staged pipeline ----------------
// Grid 49m x 8n = 392 blocks, 256 thr (4 waves). Block tile 32x128, BK=64.
// Per k-step: reg-stage 20KB (A 4.6KB + B 18.4KB padded) into LDS, prefetch
// next step's global loads under the ds_read+MFMA phase. Each wave owns a
// 32x32 output tile. Removes the exposed L2/L3 latency of per-lane loads
// (R5 counters: MfmaUtil 1.4%, VALUBusy 11% on the unstaged variant).
__global__ __launch_bounds__(256) void gemm_himg_kernel(const unsigned short* __restrict__ Xb,
                                                        const unsigned short* __restrict__ W1b,
                                                        float* __restrict__ H) {
    __shared__ unsigned short lds[160 * LROW];   // rows 0..31 = A, rows 32..159 = B; 23,040 B
    int tid = threadIdx.x;
    int wave = tid >> 6, lane = tid & 63;
    int m0 = (blockIdx.x >> 3) * 32;     // 49 m-tiles
    int n0 = (blockIdx.x & 7) * 128;     // 8 n-panels

    // staging map: thread t -> A chunk t (row t>>3, k16 t&7), B chunks t+256j (j=0..3)
    int arow = tid >> 3, ak16 = tid & 7;
    const unsigned short* gA = Xb + (size_t)(m0 + arow) * D_ + ak16 * 8;
    unsigned short* lA = &lds[arow * LROW + ak16 * 8];
    const unsigned short* gB[4];
    unsigned short* lB[4];
    #pragma unroll
    for (int j = 0; j < 4; j++) {
        int idx = tid + 256 * j;
        int brow = idx >> 3, bk16 = idx & 7;
        gB[j] = W1b + (size_t)(n0 + brow) * D_ + bk16 * 8;
        lB[j] = &lds[(32 + brow) * LROW + bk16 * 8];
    }

    // fragment read bases
    int ra = lane & 15, kq = (lane >> 4) * 8;
    const unsigned short* Af = &lds[ra * LROW + kq];
    const unsigned short* Bf = &lds[(32 + wave * 32 + ra) * LROW + kq];

    float4_t acc[2][2] = {};
    short8_t sA = *(const short8_t*)(gA);
    short8_t sB0 = *(const short8_t*)(gB[0]);
    short8_t sB1 = *(const short8_t*)(gB[1]);
    short8_t sB2 = *(const short8_t*)(gB[2]);
    short8_t sB3 = *(const short8_t*)(gB[3]);

    for (int t = 0; t < 32; t++) {
        // write staged registers to LDS
        *(short8_t*)lA = sA;
        *(short8_t*)lB[0] = sB0;
        *(short8_t*)lB[1] = sB1;
        *(short8_t*)lB[2] = sB2;
        *(short8_t*)lB[3] = sB3;
        __syncthreads();

        // prefetch next k-step from global (hides under ds_read+MFMA below)
        if (t < 31) {
            int ko = (t + 1) * 64;
            sA  = *(const short8_t*)(gA + ko);
            sB0 = *(const short8_t*)(gB[0] + ko);
            sB1 = *(const short8_t*)(gB[1] + ko);
            sB2 = *(const short8_t*)(gB[2] + ko);
            sB3 = *(const short8_t*)(gB[3] + ko);
        }

        // fragments + MFMA (BK=64 -> ks=0,1)
        #pragma unroll
        for (int ks = 0; ks < 2; ks++) {
            short8_t a0 = *(const short8_t*)(Af + ks * 32);
            short8_t a1 = *(const short8_t*)(Af + 16 * LROW + ks * 32);
            short8_t b0 = *(const short8_t*)(Bf + ks * 32);
            short8_t b1 = *(const short8_t*)(Bf + 16 * LROW + ks * 32);
            acc[0][0] = __builtin_amdgcn_mfma_f32_16x16x32_bf16(a0, b0, acc[0][0], 0, 0, 0);
            acc[0][1] = __builtin_amdgcn_mfma_f32_16x16x32_bf16(a0, b1, acc[0][1], 0, 0, 0);
            acc[1][0] = __builtin_amdgcn_mfma_f32_16x16x32_bf16(a1, b0, acc[1][0], 0, 0, 0);
            acc[1][1] = __builtin_amdgcn_mfma_f32_16x16x32_bf16(a1, b1, acc[1][1], 0, 0, 0);
        }
        __syncthreads();
    }

    int col = lane & 15, rq = (lane >> 4) * 4;
    #pragma unroll
    for (int mt = 0; mt < 2; mt++) {
        #pragma unroll
        for (int nt = 0; nt < 2; nt++) {
            float4_t v = acc[mt][nt];
            int rbase = m0 + mt * 16 + rq;
            int cidx = n0 + wave * 32 + nt * 16 + col;
            H[(rbase + 0) * I_ + cidx] = v.x;
            H[(rbase + 1) * I_ + cidx] = v.y;
            H[(rbase + 2) * I_ + cidx] = v.z;
            H[(rbase + 3) * I_ + cidx] = v.w;
        }
    }
}

// ---------------- logits: 4 spatial positions per block ----------------
__global__ __launch_bounds__(256) void logits_kernel(const float* __restrict__ H,
                                                     const float* __restrict__ hw,
                                                     const float* __restrict__ we,
                                                     const float* __restrict__ bias,
                                                     float* __restrict__ lg) {
    __shared__ float sh[4][I_];
    __shared__ float sw[I_];
    int n0 = blockIdx.x * 4, tid = threadIdx.x;
    #pragma unroll
    for (int t = 0; t < 4; t++) {
        int idx = tid + 256 * t;
        sw[idx] = we[idx];
        #pragma unroll
        for (int nn = 0; nn < 4; nn++)
            sh[nn][idx] = H[(size_t)(n0 + nn) * I_ + idx];
    }
    __syncthreads();
    int wv = tid >> 6, lane = tid & 63;
    float bz = bias[0];
    for (int j = 0; j < 5; j++) {
        int c = j * 4 + wv;
        const float* hwc = hw + c * I_;
        float a0 = 0.f, a1 = 0.f, a2 = 0.f, a3 = 0.f;
        #pragma unroll 2
        for (int i = lane; i < I_; i += 64) {
            float hv = hwc[i], wvv = sw[i];
            float x0 = sh[0][i] * hv;
            float x1 = sh[1][i] * hv;
            float x2 = sh[2][i] * hv;
            float x3 = sh[3][i] * hv;
            float t0 = 1.f - __fdividef(2.f, __expf(2.f * x0) + 1.f);
            float t1 = 1.f - __fdividef(2.f, __expf(2.f * x1) + 1.f);
            float t2 = 1.f - __fdividef(2.f, __expf(2.f * x2) + 1.f);
            float t3 = 1.f - __fdividef(2.f, __expf(2.f * x3) + 1.f);
            a0 += t0 * wvv; a1 += t1 * wvv; a2 += t2 * wvv; a3 += t3 * wvv;
        }
        #pragma unroll
        for (int o = 32; o > 0; o >>= 1) {
            a0 += __shfl_down(a0, o);
            a1 += __shfl_down(a1, o);
            a2 += __shfl_down(a2, o);
            a3 += __shfl_down(a3, o);
        }
        if (lane == 0) {
            lg[(n0 + 0) * C_ + c] = a0 + bz;
            lg[(n0 + 1) * C_ + c] = a1 + bz;
            lg[(n0 + 2) * C_ + c] = a2 + bz;
            lg[(n0 + 3) * C_ + c] = a3 + bz;
        }
    }
}

// ---------------- softmax over 196 positions per (b,c); write coef output ----------------
__global__ __launch_bounds__(256) void softmax_kernel(const float* __restrict__ lg,
                                                      float* __restrict__ coef) {
    __shared__ float r[4];
    __shared__ float bval;
    int bx = blockIdx.x;
    int b = bx / C_, c = bx % C_;
    int tid = threadIdx.x, wv = tid >> 6, lane = tid & 63;
    float v = (tid < P_) ? lg[(b * P_ + tid) * C_ + c] : -3.0e38f;
    float m = v;
    #pragma unroll
    for (int o = 32; o > 0; o >>= 1) m = fmaxf(m, __shfl_down(m, o));
    if (lane == 0) r[wv] = m;
    __syncthreads();
    if (tid == 0) bval = fmaxf(fmaxf(r[0], r[1]), fmaxf(r[2], r[3]));
    __syncthreads();
    float mx = bval;
    float e = (tid < P_) ? __expf(v - mx) : 0.f;
    float s = e;
    #pragma unroll
    for (int o = 32; o > 0; o >>= 1) s += __shfl_down(s, o);
    __syncthreads();
    if (lane == 0) r[wv] = s;
    __syncthreads();
    if (tid == 0) bval = r[0] + r[1] + r[2] + r[3];
    __syncthreads();
    if (tid < P_) coef[(b * P_ + tid) * C_ + c] = e / bval;
}

// ---------------- fmwc[b,p,c,d] = img[b,p,d] * coef[b,p,c] ----------------
__global__ __launch_bounds__(256) void fmwc_kernel(const float* __restrict__ img,
                                                   const float* __restrict__ coef,
                                                   float* __restrict__ fm) {
    __shared__ float sc[C_];
    int bp = blockIdx.x, tid = threadIdx.x;
    if (tid < C_) sc[tid] = coef[bp * C_ + tid];
    __syncthreads();
    const float4_t* ir = (const float4_t*)(img + (size_t)bp * D_);
    float4_t v0 = ir[tid], v1 = ir[tid + 256];
    float4_t* ob = (float4_t*)(fm + (size_t)bp * C_ * D_);
    #pragma unroll
    for (int c = 0; c < C_; c++) {
        float s = sc[c];
        ob[c * 512 + tid] = v0 * s;
        ob[c * 512 + tid + 256] = v1 * s;
    }
}

// ---------------- semantic partials: block (ps,b,ch) reads img once, all 20 c in regs ----------------
__global__ __launch_bounds__(256) void semantic_part_kernel(const float* __restrict__ img,
                                                            const float* __restrict__ coef,
                                                            float* __restrict__ part) {
    __shared__ float sc[PS_ * C_];
    int bx = blockIdx.x;
    int ps = bx >> 4;           // 0..13
    int b = (bx >> 1) & 7;
    int ch = bx & 1;
    int tid = threadIdx.x;
    for (int q = tid; q < PS_ * C_; q += 256)
        sc[q] = coef[(b * P_ + ps * PS_) * C_ + q];
    __syncthreads();
    const float4_t* base = (const float4_t*)(img + (size_t)(b * P_ + ps * PS_) * D_ + ch * 1024) + tid;
    float4_t acc[C_];
    #pragma unroll
    for (int c = 0; c < C_; c++) acc[c] = (float4_t){0.f, 0.f, 0.f, 0.f};
    for (int pp = 0; pp < PS_; pp++) {
        float4_t v = base[pp * 512];
        #pragma unroll
        for (int c = 0; c < C_; c++) acc[c] += v * sc[pp * C_ + c];
    }
    float* pb = part + ((size_t)(ps * B_ + b) * C_) * D_ + ch * 1024 + tid * 4;
    #pragma unroll
    for (int c = 0; c < C_; c++) *(float4_t*)(pb + c * D_) = acc[c];
}

// ---------------- semantic reduce over 14 p-splits ----------------
__global__ __launch_bounds__(256) void semantic_reduce_kernel(const float* __restrict__ part,
                                                              float* __restrict__ sem) {
    int idx = blockIdx.x * 256 + threadIdx.x;   // float4 index over B*C*D/4 = 81920
    const float4_t* p4 = (const float4_t*)part;
    float4_t s = {0.f, 0.f, 0.f, 0.f};
    #pragma unroll
    for (int ps = 0; ps < PS_; ps++) s += p4[(size_t)ps * 81920 + idx];
    ((float4_t*)sem)[idx] = s;
}

extern "C" void kernel_launch(void* const* d_in, const int* in_sizes, int n_in,
                              void* d_out, int out_size, void* d_ws, size_t ws_size,
                              hipStream_t stream) {
    const float* img = (const float*)d_in[0];
    const float* wf  = (const float*)d_in[1];
    const float* W1  = (const float*)d_in[2];
    const float* W2  = (const float*)d_in[3];
    const float* W3  = (const float*)d_in[4];
    const float* b3  = (const float*)d_in[5];
    const float* W4  = (const float*)d_in[6];
    const float* b4  = (const float*)d_in[7];

    float* out  = (float*)d_out;
    float* sem  = out;                                  // [B,C,D]      = 327680
    float* fm   = out + (size_t)B_ * C_ * D_;           // [B,S,S,C,D]  = 64225280
    float* coef = fm + (size_t)N_ * C_ * D_;            // [B,S,S,C]    = 31360

    char* ws = (char*)d_ws;
    unsigned short* Xb  = (unsigned short*)ws;                  // 6,422,528 B
    unsigned short* W1b = (unsigned short*)(ws + 6422528);      // 4,194,304 B
    float* H    = (float*)(ws + 10616832);                      // 6,422,528 B
    float* hw   = (float*)(ws + 17039360);                      // 81,920 B
    float* we   = (float*)(ws + 17121280);                      // 4,096 B
    float* bias = (float*)(ws + 17125376);                      // 256 B
    float* lg   = (float*)(ws + 17125632);                      // 125,440 B
    float* part = (float*)(ws + 17251072);                      // 14*8*20*2048*4 = 18,350,080 B

    cvt_prep_kernel<<<5281, 256, 0, stream>>>(img, W1, Xb, W1b, wf, W2, W3, b3, W4, b4, hw, we, bias);
    gemm_himg_kernel<<<392, 256, 0, stream>>>(Xb, W1b, H);
    logits_kernel<<<N_ / 4, 256, 0, stream>>>(H, hw, we, bias, lg);
    softmax_kernel<<<B_ * C_, 256, 0, stream>>>(lg, coef);
    semantic_part_kernel<<<PS_ * B_ * 2, 256, 0, stream>>>(img, coef, part);
    semantic_reduce_kernel<<<320, 256, 0, stream>>>(part, sem);
    fmwc_kernel<<<N_, 256, 0, stream>>>(img, coef, fm);
}

// Round 7
// 395.914 us; speedup vs baseline: 1.3430x; 1.0191x over previous
//
#include <hip/hip_runtime.h>

typedef __attribute__((ext_vector_type(4))) float float4_t;
typedef __attribute__((ext_vector_type(8))) short short8_t;
typedef __attribute__((ext_vector_type(4))) unsigned short ushort4_t;

#define B_ 8
#define S_ 14
#define P_ 196      // S*S
#define N_ 1568     // B*P
#define D_ 2048
#define C_ 20
#define WD_ 300
#define I_ 1024
#define PS_ 14      // p-splits in semantic partial
#define LROW 72     // LDS row stride in bf16 (64 data + 8 pad): 144B, 16B-aligned, ~2-way banks

__device__ __forceinline__ unsigned short f2bf(float f) {
    unsigned u = __builtin_bit_cast(unsigned, f);
    u += 0x7FFFu + ((u >> 16) & 1u);   // round-to-nearest-even
    return (unsigned short)(u >> 16);
}

// ---------------- fused: fp32->bf16 cvt (blocks 0..5183) + prep (5184..5280) ----------------
__global__ __launch_bounds__(256) void cvt_prep_kernel(const float* __restrict__ img,
                                                       const float* __restrict__ W1,
                                                       unsigned short* __restrict__ Xb,
                                                       unsigned short* __restrict__ W1b,
                                                       const float* __restrict__ wf,
                                                       const float* __restrict__ W2,
                                                       const float* __restrict__ W3,
                                                       const float* __restrict__ b3,
                                                       const float* __restrict__ W4,
                                                       const float* __restrict__ b4,
                                                       float* __restrict__ hw,
                                                       float* __restrict__ we,
                                                       float* __restrict__ bias) {
    int bid = blockIdx.x, tid = threadIdx.x;
    if (bid < 5184) {
        const float* src;
        unsigned short* dst;
        int i4;
        if (bid < 3136) { i4 = bid * 256 + tid; src = img; dst = Xb; }
        else            { i4 = (bid - 3136) * 256 + tid; src = W1; dst = W1b; }
        float4_t v = ((const float4_t*)src)[i4];
        ushort4_t o;
        o.x = f2bf(v.x); o.y = f2bf(v.y); o.z = f2bf(v.z); o.w = f2bf(v.w);
        ((ushort4_t*)dst)[i4] = o;
        return;
    }
    int pb = bid - 5184;
    if (pb < 80) {
        // hw[c,i] = sum_k wf[c,k] * W2[i,k]
        int idx = pb * 256 + tid;
        int c = idx >> 10, i = idx & 1023;
        const float* wr  = wf + c * WD_;
        const float* w2r = W2 + i * WD_;
        float s = 0.f;
        #pragma unroll 4
        for (int k = 0; k < WD_; k++) s += wr[k] * w2r[k];
        hw[idx] = s;
    } else if (pb < 96) {
        // we[i] = sum_j W4[j] * W3[j,i]; 16 blocks x 64 cols, 4-way j split
        __shared__ float red[256];
        int blk = pb - 80;
        int i0 = blk * 64;
        int q = tid >> 6, col = tid & 63;
        float s = 0.f;
        #pragma unroll 4
        for (int j = q * 256; j < q * 256 + 256; j++)
            s += W4[j] * W3[j * I_ + i0 + col];
        red[tid] = s;
        __syncthreads();
        if (tid < 64)
            we[i0 + tid] = red[tid] + red[tid + 64] + red[tid + 128] + red[tid + 192];
    } else {
        // bias = dot(b3, W4) + b4[0]
        __shared__ float r[256];
        float s = 0.f;
        for (int j = tid; j < I_; j += 256) s += b3[j] * W4[j];
        r[tid] = s;
        __syncthreads();
        for (int o = 128; o > 0; o >>= 1) {
            if (tid < o) r[tid] += r[tid + o];
            __syncthreads();
        }
        if (tid == 0) bias[0] = r[0] + b4[0];
    }
}

// ---------------- h_img = X @ W1^T, LDS-staged pipeline (R6-verified) ----------------
__global__ __launch_bounds__(256) void gemm_himg_kernel(const unsigned short* __restrict__ Xb,
                                                        const unsigned short* __restrict__ W1b,
                                                        float* __restrict__ H) {
    __shared__ unsigned short lds[160 * LROW];   // rows 0..31 = A, rows 32..159 = B; 23,040 B
    int tid = threadIdx.x;
    int wave = tid >> 6, lane = tid & 63;
    int m0 = (blockIdx.x >> 3) * 32;     // 49 m-tiles
    int n0 = (blockIdx.x & 7) * 128;     // 8 n-panels

    int arow = tid >> 3, ak16 = tid & 7;
    const unsigned short* gA = Xb + (size_t)(m0 + arow) * D_ + ak16 * 8;
    unsigned short* lA = &lds[arow * LROW + ak16 * 8];
    const unsigned short* gB[4];
    unsigned short* lB[4];
    #pragma unroll
    for (int j = 0; j < 4; j++) {
        int idx = tid + 256 * j;
        int brow = idx >> 3, bk16 = idx & 7;
        gB[j] = W1b + (size_t)(n0 + brow) * D_ + bk16 * 8;
        lB[j] = &lds[(32 + brow) * LROW + bk16 * 8];
    }

    int ra = lane & 15, kq = (lane >> 4) * 8;
    const unsigned short* Af = &lds[ra * LROW + kq];
    const unsigned short* Bf = &lds[(32 + wave * 32 + ra) * LROW + kq];

    float4_t acc[2][2] = {};
    short8_t sA = *(const short8_t*)(gA);
    short8_t sB0 = *(const short8_t*)(gB[0]);
    short8_t sB1 = *(const short8_t*)(gB[1]);
    short8_t sB2 = *(const short8_t*)(gB[2]);
    short8_t sB3 = *(const short8_t*)(gB[3]);

    for (int t = 0; t < 32; t++) {
        *(short8_t*)lA = sA;
        *(short8_t*)lB[0] = sB0;
        *(short8_t*)lB[1] = sB1;
        *(short8_t*)lB[2] = sB2;
        *(short8_t*)lB[3] = sB3;
        __syncthreads();

        if (t < 31) {
            int ko = (t + 1) * 64;
            sA  = *(const short8_t*)(gA + ko);
            sB0 = *(const short8_t*)(gB[0] + ko);
            sB1 = *(const short8_t*)(gB[1] + ko);
            sB2 = *(const short8_t*)(gB[2] + ko);
            sB3 = *(const short8_t*)(gB[3] + ko);
        }

        #pragma unroll
        for (int ks = 0; ks < 2; ks++) {
            short8_t a0 = *(const short8_t*)(Af + ks * 32);
            short8_t a1 = *(const short8_t*)(Af + 16 * LROW + ks * 32);
            short8_t b0 = *(const short8_t*)(Bf + ks * 32);
            short8_t b1 = *(const short8_t*)(Bf + 16 * LROW + ks * 32);
            acc[0][0] = __builtin_amdgcn_mfma_f32_16x16x32_bf16(a0, b0, acc[0][0], 0, 0, 0);
            acc[0][1] = __builtin_amdgcn_mfma_f32_16x16x32_bf16(a0, b1, acc[0][1], 0, 0, 0);
            acc[1][0] = __builtin_amdgcn_mfma_f32_16x16x32_bf16(a1, b0, acc[1][0], 0, 0, 0);
            acc[1][1] = __builtin_amdgcn_mfma_f32_16x16x32_bf16(a1, b1, acc[1][1], 0, 0, 0);
        }
        __syncthreads();
    }

    int col = lane & 15, rq = (lane >> 4) * 4;
    #pragma unroll
    for (int mt = 0; mt < 2; mt++) {
        #pragma unroll
        for (int nt = 0; nt < 2; nt++) {
            float4_t v = acc[mt][nt];
            int rbase = m0 + mt * 16 + rq;
            int cidx = n0 + wave * 32 + nt * 16 + col;
            H[(rbase + 0) * I_ + cidx] = v.x;
            H[(rbase + 1) * I_ + cidx] = v.y;
            H[(rbase + 2) * I_ + cidx] = v.z;
            H[(rbase + 3) * I_ + cidx] = v.w;
        }
    }
}

// ---------------- logits: 2 rows/block, 784 blocks (3.06/CU), 4-ILP via class pairs ----------------
// R6 inference: logits ~40us at 392 blocks (1.53/CU, latency-exposed). Double the
// block count at constant arithmetic; per-(n,c) accumulation order unchanged (bitwise).
__global__ __launch_bounds__(256) void logits_kernel(const float* __restrict__ H,
                                                     const float* __restrict__ hw,
                                                     const float* __restrict__ we,
                                                     const float* __restrict__ bias,
                                                     float* __restrict__ lg) {
    __shared__ float sh[2][I_];
    __shared__ float sw[I_];
    int n0 = blockIdx.x * 2, tid = threadIdx.x;
    #pragma unroll
    for (int t = 0; t < 4; t++) {
        int idx = tid + 256 * t;
        sw[idx] = we[idx];
        sh[0][idx] = H[(size_t)n0 * I_ + idx];
        sh[1][idx] = H[(size_t)(n0 + 1) * I_ + idx];
    }
    __syncthreads();
    int wv = tid >> 6, lane = tid & 63;
    float bz = bias[0];

    // class pairs: jj=0 -> (wv, 4+wv); jj=1 -> (8+wv, 12+wv); leftover 16+wv
    #pragma unroll
    for (int jj = 0; jj < 2; jj++) {
        int c0 = jj * 8 + wv, c1 = c0 + 4;
        const float* h0 = hw + c0 * I_;
        const float* h1 = hw + c1 * I_;
        float a00 = 0.f, a01 = 0.f, a10 = 0.f, a11 = 0.f;
        #pragma unroll 2
        for (int i = lane; i < I_; i += 64) {
            float s0 = sh[0][i], s1 = sh[1][i], wvv = sw[i];
            float hv0 = h0[i], hv1 = h1[i];
            float x00 = s0 * hv0, x01 = s0 * hv1;
            float x10 = s1 * hv0, x11 = s1 * hv1;
            float t00 = 1.f - __fdividef(2.f, __expf(2.f * x00) + 1.f);
            float t01 = 1.f - __fdividef(2.f, __expf(2.f * x01) + 1.f);
            float t10 = 1.f - __fdividef(2.f, __expf(2.f * x10) + 1.f);
            float t11 = 1.f - __fdividef(2.f, __expf(2.f * x11) + 1.f);
            a00 += t00 * wvv; a01 += t01 * wvv;
            a10 += t10 * wvv; a11 += t11 * wvv;
        }
        #pragma unroll
        for (int o = 32; o > 0; o >>= 1) {
            a00 += __shfl_down(a00, o);
            a01 += __shfl_down(a01, o);
            a10 += __shfl_down(a10, o);
            a11 += __shfl_down(a11, o);
        }
        if (lane == 0) {
            lg[n0 * C_ + c0] = a00 + bz;
            lg[n0 * C_ + c1] = a01 + bz;
            lg[(n0 + 1) * C_ + c0] = a10 + bz;
            lg[(n0 + 1) * C_ + c1] = a11 + bz;
        }
    }
    {
        int c = 16 + wv;
        const float* h0 = hw + c * I_;
        float a0 = 0.f, a1 = 0.f;
        #pragma unroll 2
        for (int i = lane; i < I_; i += 64) {
            float wvv = sw[i];
            float hv = h0[i];
            float x0 = sh[0][i] * hv;
            float x1 = sh[1][i] * hv;
            float t0 = 1.f - __fdividef(2.f, __expf(2.f * x0) + 1.f);
            float t1 = 1.f - __fdividef(2.f, __expf(2.f * x1) + 1.f);
            a0 += t0 * wvv; a1 += t1 * wvv;
        }
        #pragma unroll
        for (int o = 32; o > 0; o >>= 1) {
            a0 += __shfl_down(a0, o);
            a1 += __shfl_down(a1, o);
        }
        if (lane == 0) {
            lg[n0 * C_ + c] = a0 + bz;
            lg[(n0 + 1) * C_ + c] = a1 + bz;
        }
    }
}

// ---------------- softmax over 196 positions per (b,c); write coef output ----------------
__global__ __launch_bounds__(256) void softmax_kernel(const float* __restrict__ lg,
                                                      float* __restrict__ coef) {
    __shared__ float r[4];
    __shared__ float bval;
    int bx = blockIdx.x;
    int b = bx / C_, c = bx % C_;
    int tid = threadIdx.x, wv = tid >> 6, lane = tid & 63;
    float v = (tid < P_) ? lg[(b * P_ + tid) * C_ + c] : -3.0e38f;
    float m = v;
    #pragma unroll
    for (int o = 32; o > 0; o >>= 1) m = fmaxf(m, __shfl_down(m, o));
    if (lane == 0) r[wv] = m;
    __syncthreads();
    if (tid == 0) bval = fmaxf(fmaxf(r[0], r[1]), fmaxf(r[2], r[3]));
    __syncthreads();
    float mx = bval;
    float e = (tid < P_) ? __expf(v - mx) : 0.f;
    float s = e;
    #pragma unroll
    for (int o = 32; o > 0; o >>= 1) s += __shfl_down(s, o);
    __syncthreads();
    if (lane == 0) r[wv] = s;
    __syncthreads();
    if (tid == 0) bval = r[0] + r[1] + r[2] + r[3];
    __syncthreads();
    if (tid < P_) coef[(b * P_ + tid) * C_ + c] = e / bval;
}

// ---------------- fmwc[b,p,c,d] = img[b,p,d] * coef[b,p,c] ----------------
__global__ __launch_bounds__(256) void fmwc_kernel(const float* __restrict__ img,
                                                   const float* __restrict__ coef,
                                                   float* __restrict__ fm) {
    __shared__ float sc[C_];
    int bp = blockIdx.x, tid = threadIdx.x;
    if (tid < C_) sc[tid] = coef[bp * C_ + tid];
    __syncthreads();
    const float4_t* ir = (const float4_t*)(img + (size_t)bp * D_);
    float4_t v0 = ir[tid], v1 = ir[tid + 256];
    float4_t* ob = (float4_t*)(fm + (size_t)bp * C_ * D_);
    #pragma unroll
    for (int c = 0; c < C_; c++) {
        float s = sc[c];
        ob[c * 512 + tid] = v0 * s;
        ob[c * 512 + tid + 256] = v1 * s;
    }
}

// ---------------- semantic partials: block (ps,b,ch) reads img once, all 20 c in regs ----------------
__global__ __launch_bounds__(256) void semantic_part_kernel(const float* __restrict__ img,
                                                            const float* __restrict__ coef,
                                                            float* __restrict__ part) {
    __shared__ float sc[PS_ * C_];
    int bx = blockIdx.x;
    int ps = bx >> 4;           // 0..13
    int b = (bx >> 1) & 7;
    int ch = bx & 1;
    int tid = threadIdx.x;
    for (int q = tid; q < PS_ * C_; q += 256)
        sc[q] = coef[(b * P_ + ps * PS_) * C_ + q];
    __syncthreads();
    const float4_t* base = (const float4_t*)(img + (size_t)(b * P_ + ps * PS_) * D_ + ch * 1024) + tid;
    float4_t acc[C_];
    #pragma unroll
    for (int c = 0; c < C_; c++) acc[c] = (float4_t){0.f, 0.f, 0.f, 0.f};
    for (int pp = 0; pp < PS_; pp++) {
        float4_t v = base[pp * 512];
        #pragma unroll
        for (int c = 0; c < C_; c++) acc[c] += v * sc[pp * C_ + c];
    }
    float* pb = part + ((size_t)(ps * B_ + b) * C_) * D_ + ch * 1024 + tid * 4;
    #pragma unroll
    for (int c = 0; c < C_; c++) *(float4_t*)(pb + c * D_) = acc[c];
}

// ---------------- semantic reduce over 14 p-splits ----------------
__global__ __launch_bounds__(256) void semantic_reduce_kernel(const float* __restrict__ part,
                                                              float* __restrict__ sem) {
    int idx = blockIdx.x * 256 + threadIdx.x;   // float4 index over B*C*D/4 = 81920
    const float4_t* p4 = (const float4_t*)part;
    float4_t s = {0.f, 0.f, 0.f, 0.f};
    #pragma unroll
    for (int ps = 0; ps < PS_; ps++) s += p4[(size_t)ps * 81920 + idx];
    ((float4_t*)sem)[idx] = s;
}

extern "C" void kernel_launch(void* const* d_in, const int* in_sizes, int n_in,
                              void* d_out, int out_size, void* d_ws, size_t ws_size,
                              hipStream_t stream) {
    const float* img = (const float*)d_in[0];
    const float* wf  = (const float*)d_in[1];
    const float* W1  = (const float*)d_in[2];
    const float* W2  = (const float*)d_in[3];
    const float* W3  = (const float*)d_in[4];
    const float* b3  = (const float*)d_in[5];
    const float* W4  = (const float*)d_in[6];
    const float* b4  = (const float*)d_in[7];

    float* out  = (float*)d_out;
    float* sem  = out;                                  // [B,C,D]      = 327680
    float* fm   = out + (size_t)B_ * C_ * D_;           // [B,S,S,C,D]  = 64225280
    float* coef = fm + (size_t)N_ * C_ * D_;            // [B,S,S,C]    = 31360

    char* ws = (char*)d_ws;
    unsigned short* Xb  = (unsigned short*)ws;                  // 6,422,528 B
    unsigned short* W1b = (unsigned short*)(ws + 6422528);      // 4,194,304 B
    float* H    = (float*)(ws + 10616832);                      // 6,422,528 B
    float* hw   = (float*)(ws + 17039360);                      // 81,920 B
    float* we   = (float*)(ws + 17121280);                      // 4,096 B
    float* bias = (float*)(ws + 17125376);                      // 256 B
    float* lg   = (float*)(ws + 17125632);                      // 125,440 B
    float* part = (float*)(ws + 17251072);                      // 14*8*20*2048*4 = 18,350,080 B

    cvt_prep_kernel<<<5281, 256, 0, stream>>>(img, W1, Xb, W1b, wf, W2, W3, b3, W4, b4, hw, we, bias);
    gemm_himg_kernel<<<392, 256, 0, stream>>>(Xb, W1b, H);
    logits_kernel<<<N_ / 2, 256, 0, stream>>>(H, hw, we, bias, lg);
    softmax_kernel<<<B_ * C_, 256, 0, stream>>>(lg, coef);
    semantic_part_kernel<<<PS_ * B_ * 2, 256, 0, stream>>>(img, coef, part);
    semantic_reduce_kernel<<<320, 256, 0, stream>>>(part, sem);
    fmwc_kernel<<<N_, 256, 0, stream>>>(img, coef, fm);
}

// Round 8
// 388.713 us; speedup vs baseline: 1.3679x; 1.0185x over previous
//
#include <hip/hip_runtime.h>

typedef __attribute__((ext_vector_type(4))) float float4_t;
typedef __attribute__((ext_vector_type(8))) short short8_t;
typedef __attribute__((ext_vector_type(4))) unsigned short ushort4_t;

#define B_ 8
#define S_ 14
#define P_ 196      // S*S
#define N_ 1568     // B*P
#define D_ 2048
#define C_ 20
#define WD_ 300
#define I_ 1024
#define PS_ 14      // p-splits in semantic partial
#define LROW 72     // LDS row stride in bf16 (64 data + 8 pad): 144B, 16B-aligned, ~2-way banks

__device__ __forceinline__ unsigned short f2bf(float f) {
    unsigned u = __builtin_bit_cast(unsigned, f);
    u += 0x7FFFu + ((u >> 16) & 1u);   // round-to-nearest-even
    return (unsigned short)(u >> 16);
}

// ---------------- fused: fp32->bf16 cvt (blocks 0..5183) + prep (5184..5280) ----------------
__global__ __launch_bounds__(256) void cvt_prep_kernel(const float* __restrict__ img,
                                                       const float* __restrict__ W1,
                                                       unsigned short* __restrict__ Xb,
                                                       unsigned short* __restrict__ W1b,
                                                       const float* __restrict__ wf,
                                                       const float* __restrict__ W2,
                                                       const float* __restrict__ W3,
                                                       const float* __restrict__ b3,
                                                       const float* __restrict__ W4,
                                                       const float* __restrict__ b4,
                                                       float* __restrict__ hw,
                                                       float* __restrict__ we,
                                                       float* __restrict__ bias) {
    int bid = blockIdx.x, tid = threadIdx.x;
    if (bid < 5184) {
        const float* src;
        unsigned short* dst;
        int i4;
        if (bid < 3136) { i4 = bid * 256 + tid; src = img; dst = Xb; }
        else            { i4 = (bid - 3136) * 256 + tid; src = W1; dst = W1b; }
        float4_t v = ((const float4_t*)src)[i4];
        ushort4_t o;
        o.x = f2bf(v.x); o.y = f2bf(v.y); o.z = f2bf(v.z); o.w = f2bf(v.w);
        ((ushort4_t*)dst)[i4] = o;
        return;
    }
    int pb = bid - 5184;
    if (pb < 80) {
        // hw[c,i] = sum_k wf[c,k] * W2[i,k]
        int idx = pb * 256 + tid;
        int c = idx >> 10, i = idx & 1023;
        const float* wr  = wf + c * WD_;
        const float* w2r = W2 + i * WD_;
        float s = 0.f;
        #pragma unroll 4
        for (int k = 0; k < WD_; k++) s += wr[k] * w2r[k];
        hw[idx] = s;
    } else if (pb < 96) {
        // we[i] = sum_j W4[j] * W3[j,i]; 16 blocks x 64 cols, 4-way j split
        __shared__ float red[256];
        int blk = pb - 80;
        int i0 = blk * 64;
        int q = tid >> 6, col = tid & 63;
        float s = 0.f;
        #pragma unroll 4
        for (int j = q * 256; j < q * 256 + 256; j++)
            s += W4[j] * W3[j * I_ + i0 + col];
        red[tid] = s;
        __syncthreads();
        if (tid < 64)
            we[i0 + tid] = red[tid] + red[tid + 64] + red[tid + 128] + red[tid + 192];
    } else {
        // bias = dot(b3, W4) + b4[0]
        __shared__ float r[256];
        float s = 0.f;
        for (int j = tid; j < I_; j += 256) s += b3[j] * W4[j];
        r[tid] = s;
        __syncthreads();
        for (int o = 128; o > 0; o >>= 1) {
            if (tid < o) r[tid] += r[tid + o];
            __syncthreads();
        }
        if (tid == 0) bias[0] = r[0] + b4[0];
    }
}

// ---------------- h_img = X @ W1^T, LDS-staged pipeline (R6-verified) ----------------
__global__ __launch_bounds__(256) void gemm_himg_kernel(const unsigned short* __restrict__ Xb,
                                                        const unsigned short* __restrict__ W1b,
                                                        float* __restrict__ H) {
    __shared__ unsigned short lds[160 * LROW];   // rows 0..31 = A, rows 32..159 = B; 23,040 B
    int tid = threadIdx.x;
    int wave = tid >> 6, lane = tid & 63;
    int m0 = (blockIdx.x >> 3) * 32;     // 49 m-tiles
    int n0 = (blockIdx.x & 7) * 128;     // 8 n-panels

    int arow = tid >> 3, ak16 = tid & 7;
    const unsigned short* gA = Xb + (size_t)(m0 + arow) * D_ + ak16 * 8;
    unsigned short* lA = &lds[arow * LROW + ak16 * 8];
    const unsigned short* gB[4];
    unsigned short* lB[4];
    #pragma unroll
    for (int j = 0; j < 4; j++) {
        int idx = tid + 256 * j;
        int brow = idx >> 3, bk16 = idx & 7;
        gB[j] = W1b + (size_t)(n0 + brow) * D_ + bk16 * 8;
        lB[j] = &lds[(32 + brow) * LROW + bk16 * 8];
    }

    int ra = lane & 15, kq = (lane >> 4) * 8;
    const unsigned short* Af = &lds[ra * LROW + kq];
    const unsigned short* Bf = &lds[(32 + wave * 32 + ra) * LROW + kq];

    float4_t acc[2][2] = {};
    short8_t sA = *(const short8_t*)(gA);
    short8_t sB0 = *(const short8_t*)(gB[0]);
    short8_t sB1 = *(const short8_t*)(gB[1]);
    short8_t sB2 = *(const short8_t*)(gB[2]);
    short8_t sB3 = *(const short8_t*)(gB[3]);

    for (int t = 0; t < 32; t++) {
        *(short8_t*)lA = sA;
        *(short8_t*)lB[0] = sB0;
        *(short8_t*)lB[1] = sB1;
        *(short8_t*)lB[2] = sB2;
        *(short8_t*)lB[3] = sB3;
        __syncthreads();

        if (t < 31) {
            int ko = (t + 1) * 64;
            sA  = *(const short8_t*)(gA + ko);
            sB0 = *(const short8_t*)(gB[0] + ko);
            sB1 = *(const short8_t*)(gB[1] + ko);
            sB2 = *(const short8_t*)(gB[2] + ko);
            sB3 = *(const short8_t*)(gB[3] + ko);
        }

        #pragma unroll
        for (int ks = 0; ks < 2; ks++) {
            short8_t a0 = *(const short8_t*)(Af + ks * 32);
            short8_t a1 = *(const short8_t*)(Af + 16 * LROW + ks * 32);
            short8_t b0 = *(const short8_t*)(Bf + ks * 32);
            short8_t b1 = *(const short8_t*)(Bf + 16 * LROW + ks * 32);
            acc[0][0] = __builtin_amdgcn_mfma_f32_16x16x32_bf16(a0, b0, acc[0][0], 0, 0, 0);
            acc[0][1] = __builtin_amdgcn_mfma_f32_16x16x32_bf16(a0, b1, acc[0][1], 0, 0, 0);
            acc[1][0] = __builtin_amdgcn_mfma_f32_16x16x32_bf16(a1, b0, acc[1][0], 0, 0, 0);
            acc[1][1] = __builtin_amdgcn_mfma_f32_16x16x32_bf16(a1, b1, acc[1][1], 0, 0, 0);
        }
        __syncthreads();
    }

    int col = lane & 15, rq = (lane >> 4) * 4;
    #pragma unroll
    for (int mt = 0; mt < 2; mt++) {
        #pragma unroll
        for (int nt = 0; nt < 2; nt++) {
            float4_t v = acc[mt][nt];
            int rbase = m0 + mt * 16 + rq;
            int cidx = n0 + wave * 32 + nt * 16 + col;
            H[(rbase + 0) * I_ + cidx] = v.x;
            H[(rbase + 1) * I_ + cidx] = v.y;
            H[(rbase + 2) * I_ + cidx] = v.z;
            H[(rbase + 3) * I_ + cidx] = v.w;
        }
    }
}

// ---------------- logits: 1 row/block, 1568 blocks (6.1/CU), 5-chain ILP per wave ----------------
// R7 evidence: 392->784 blocks paid +7.6us; same mechanism once more. Per-(n,c)
// accumulation order unchanged (lane-stride-64 + same shfl tree): bitwise identical.
__global__ __launch_bounds__(256) void logits_kernel(const float* __restrict__ H,
                                                     const float* __restrict__ hw,
                                                     const float* __restrict__ we,
                                                     const float* __restrict__ bias,
                                                     float* __restrict__ lg) {
    __shared__ float sh[I_];
    __shared__ float sw[I_];
    int n = blockIdx.x, tid = threadIdx.x;
    #pragma unroll
    for (int t = 0; t < 4; t++) {
        int idx = tid + 256 * t;
        sw[idx] = we[idx];
        sh[idx] = H[(size_t)n * I_ + idx];
    }
    __syncthreads();
    int wv = tid >> 6, lane = tid & 63;
    float bz = bias[0];

    // wave wv owns classes {wv, 4+wv, 8+wv, 12+wv, 16+wv}: 5 independent chains
    int c0 = wv, c1 = 4 + wv, c2 = 8 + wv, c3 = 12 + wv, c4 = 16 + wv;
    const float* h0 = hw + c0 * I_;
    const float* h1 = hw + c1 * I_;
    const float* h2 = hw + c2 * I_;
    const float* h3 = hw + c3 * I_;
    const float* h4 = hw + c4 * I_;
    float a0 = 0.f, a1 = 0.f, a2 = 0.f, a3 = 0.f, a4 = 0.f;
    #pragma unroll 2
    for (int i = lane; i < I_; i += 64) {
        float s = sh[i], wvv = sw[i];
        float x0 = s * h0[i];
        float x1 = s * h1[i];
        float x2 = s * h2[i];
        float x3 = s * h3[i];
        float x4 = s * h4[i];
        float t0 = 1.f - __fdividef(2.f, __expf(2.f * x0) + 1.f);
        float t1 = 1.f - __fdividef(2.f, __expf(2.f * x1) + 1.f);
        float t2 = 1.f - __fdividef(2.f, __expf(2.f * x2) + 1.f);
        float t3 = 1.f - __fdividef(2.f, __expf(2.f * x3) + 1.f);
        float t4 = 1.f - __fdividef(2.f, __expf(2.f * x4) + 1.f);
        a0 += t0 * wvv; a1 += t1 * wvv; a2 += t2 * wvv; a3 += t3 * wvv; a4 += t4 * wvv;
    }
    #pragma unroll
    for (int o = 32; o > 0; o >>= 1) {
        a0 += __shfl_down(a0, o);
        a1 += __shfl_down(a1, o);
        a2 += __shfl_down(a2, o);
        a3 += __shfl_down(a3, o);
        a4 += __shfl_down(a4, o);
    }
    if (lane == 0) {
        lg[n * C_ + c0] = a0 + bz;
        lg[n * C_ + c1] = a1 + bz;
        lg[n * C_ + c2] = a2 + bz;
        lg[n * C_ + c3] = a3 + bz;
        lg[n * C_ + c4] = a4 + bz;
    }
}

// ---------------- softmax over 196 positions per (b,c); write coef output ----------------
__global__ __launch_bounds__(256) void softmax_kernel(const float* __restrict__ lg,
                                                      float* __restrict__ coef) {
    __shared__ float r[4];
    __shared__ float bval;
    int bx = blockIdx.x;
    int b = bx / C_, c = bx % C_;
    int tid = threadIdx.x, wv = tid >> 6, lane = tid & 63;
    float v = (tid < P_) ? lg[(b * P_ + tid) * C_ + c] : -3.0e38f;
    float m = v;
    #pragma unroll
    for (int o = 32; o > 0; o >>= 1) m = fmaxf(m, __shfl_down(m, o));
    if (lane == 0) r[wv] = m;
    __syncthreads();
    if (tid == 0) bval = fmaxf(fmaxf(r[0], r[1]), fmaxf(r[2], r[3]));
    __syncthreads();
    float mx = bval;
    float e = (tid < P_) ? __expf(v - mx) : 0.f;
    float s = e;
    #pragma unroll
    for (int o = 32; o > 0; o >>= 1) s += __shfl_down(s, o);
    __syncthreads();
    if (lane == 0) r[wv] = s;
    __syncthreads();
    if (tid == 0) bval = r[0] + r[1] + r[2] + r[3];
    __syncthreads();
    if (tid < P_) coef[(b * P_ + tid) * C_ + c] = e / bval;
}

// ---------------- merged: semantic partials (blocks 0..223) + fmwc (224..1791) ----------------
// Both depend only on coef; disjoint outputs; unchanged inner code -> one fewer dispatch.
__global__ __launch_bounds__(256) void part_fmwc_kernel(const float* __restrict__ img,
                                                        const float* __restrict__ coef,
                                                        float* __restrict__ part,
                                                        float* __restrict__ fm) {
    int bid = blockIdx.x, tid = threadIdx.x;
    if (bid < 224) {
        // semantic partials: block (ps,b,ch) reads img once, all 20 c in regs
        __shared__ float sc[PS_ * C_];
        int ps = bid >> 4;          // 0..13
        int b = (bid >> 1) & 7;
        int ch = bid & 1;
        for (int q = tid; q < PS_ * C_; q += 256)
            sc[q] = coef[(b * P_ + ps * PS_) * C_ + q];
        __syncthreads();
        const float4_t* base = (const float4_t*)(img + (size_t)(b * P_ + ps * PS_) * D_ + ch * 1024) + tid;
        float4_t acc[C_];
        #pragma unroll
        for (int c = 0; c < C_; c++) acc[c] = (float4_t){0.f, 0.f, 0.f, 0.f};
        for (int pp = 0; pp < PS_; pp++) {
            float4_t v = base[pp * 512];
            #pragma unroll
            for (int c = 0; c < C_; c++) acc[c] += v * sc[pp * C_ + c];
        }
        float* pb = part + ((size_t)(ps * B_ + b) * C_) * D_ + ch * 1024 + tid * 4;
        #pragma unroll
        for (int c = 0; c < C_; c++) *(float4_t*)(pb + c * D_) = acc[c];
    } else {
        // fmwc[b,p,c,d] = img[b,p,d] * coef[b,p,c]
        __shared__ float sc2[C_];
        int bp = bid - 224;
        if (tid < C_) sc2[tid] = coef[bp * C_ + tid];
        __syncthreads();
        const float4_t* ir = (const float4_t*)(img + (size_t)bp * D_);
        float4_t v0 = ir[tid], v1 = ir[tid + 256];
        float4_t* ob = (float4_t*)(fm + (size_t)bp * C_ * D_);
        #pragma unroll
        for (int c = 0; c < C_; c++) {
            float s = sc2[c];
            ob[c * 512 + tid] = v0 * s;
            ob[c * 512 + tid + 256] = v1 * s;
        }
    }
}

// ---------------- semantic reduce over 14 p-splits ----------------
__global__ __launch_bounds__(256) void semantic_reduce_kernel(const float* __restrict__ part,
                                                              float* __restrict__ sem) {
    int idx = blockIdx.x * 256 + threadIdx.x;   // float4 index over B*C*D/4 = 81920
    const float4_t* p4 = (const float4_t*)part;
    float4_t s = {0.f, 0.f, 0.f, 0.f};
    #pragma unroll
    for (int ps = 0; ps < PS_; ps++) s += p4[(size_t)ps * 81920 + idx];
    ((float4_t*)sem)[idx] = s;
}

extern "C" void kernel_launch(void* const* d_in, const int* in_sizes, int n_in,
                              void* d_out, int out_size, void* d_ws, size_t ws_size,
                              hipStream_t stream) {
    const float* img = (const float*)d_in[0];
    const float* wf  = (const float*)d_in[1];
    const float* W1  = (const float*)d_in[2];
    const float* W2  = (const float*)d_in[3];
    const float* W3  = (const float*)d_in[4];
    const float* b3  = (const float*)d_in[5];
    const float* W4  = (const float*)d_in[6];
    const float* b4  = (const float*)d_in[7];

    float* out  = (float*)d_out;
    float* sem  = out;                                  // [B,C,D]      = 327680
    float* fm   = out + (size_t)B_ * C_ * D_;           // [B,S,S,C,D]  = 64225280
    float* coef = fm + (size_t)N_ * C_ * D_;            // [B,S,S,C]    = 31360

    char* ws = (char*)d_ws;
    unsigned short* Xb  = (unsigned short*)ws;                  // 6,422,528 B
    unsigned short* W1b = (unsigned short*)(ws + 6422528);      // 4,194,304 B
    float* H    = (float*)(ws + 10616832);                      // 6,422,528 B
    float* hw   = (float*)(ws + 17039360);                      // 81,920 B
    float* we   = (float*)(ws + 17121280);                      // 4,096 B
    float* bias = (float*)(ws + 17125376);                      // 256 B
    float* lg   = (float*)(ws + 17125632);                      // 125,440 B
    float* part = (float*)(ws + 17251072);                      // 14*8*20*2048*4 = 18,350,080 B

    cvt_prep_kernel<<<5281, 256, 0, stream>>>(img, W1, Xb, W1b, wf, W2, W3, b3, W4, b4, hw, we, bias);
    gemm_himg_kernel<<<392, 256, 0, stream>>>(Xb, W1b, H);
    logits_kernel<<<N_, 256, 0, stream>>>(H, hw, we, bias, lg);
    softmax_kernel<<<B_ * C_, 256, 0, stream>>>(lg, coef);
    part_fmwc_kernel<<<224 + N_, 256, 0, stream>>>(img, coef, part, fm);
    semantic_reduce_kernel<<<320, 256, 0, stream>>>(part, sem);
}